// Round 4
// baseline (650.321 us; speedup 1.0000x reference)
//
#include <hip/hip_runtime.h>
#include <hip/hip_bf16.h>
#include <stdint.h>

// Problem constants (QuantizedLinear_22849226015470)
#define MROWS 8192      // 4*2048 activation rows
#define K_TOT 4096      // in_features
#define N_TOT 4096      // out_features
// trellis: NB=65536 tiles (256 out-tiles x 256 in-tiles of 16x16), 32 x 16-bit
// words per tile; state_t = 16-bit big-endian window at bit 2t (circular 512).
//
// Identity: out = (x·(I⊗H))·Wˢᵀ = x·(Wˢ·(I⊗H))ᵀ (H128 symmetric); scale
// commutes with H within each 128-group. Weights are decoded+rotated via MFMA
// in prep_k; the activation path is a pure fp32→bf16 convert.

typedef __attribute__((ext_vector_type(8))) short bf16x8;
typedef __attribute__((ext_vector_type(4))) float f32x4;
typedef __attribute__((ext_vector_type(8))) unsigned short ushort8;

#define GLB(p) ((const __attribute__((address_space(1))) void*)(p))
#define LDSP(p) ((__attribute__((address_space(3))) void*)(p))

#define CONV_BLOCKS 16384  // 33.5M elems / (256 thr * 8 elems)
#define DEC_BLOCKS  2048   // 8192 strips (16 rows x 128 cols) / 4 per block

// ---------------- Fused prep -----------------------------------------------
__global__ __launch_bounds__(256) void prep_k(const float* __restrict__ in,
                                              const int* __restrict__ trellis,
                                              const float* __restrict__ tlut,
                                              const float* __restrict__ scales,
                                              __hip_bfloat16* __restrict__ xb,
                                              __hip_bfloat16* __restrict__ wb) {
    const int tid = threadIdx.x;
    if (blockIdx.x < CONV_BLOCKS) {
        // ---- activation convert: 8 elems/thread, 16B in / 16B out ----
        const long base = ((long)blockIdx.x * 256 + tid) * 8;
        float4 x0 = *(const float4*)(in + base);
        float4 x1 = *(const float4*)(in + base + 4);
        ushort8 u;
        __hip_bfloat16 h;
        h = __float2bfloat16(x0.x); u[0] = *(unsigned short*)&h;
        h = __float2bfloat16(x0.y); u[1] = *(unsigned short*)&h;
        h = __float2bfloat16(x0.z); u[2] = *(unsigned short*)&h;
        h = __float2bfloat16(x0.w); u[3] = *(unsigned short*)&h;
        h = __float2bfloat16(x1.x); u[4] = *(unsigned short*)&h;
        h = __float2bfloat16(x1.y); u[5] = *(unsigned short*)&h;
        h = __float2bfloat16(x1.z); u[6] = *(unsigned short*)&h;
        h = __float2bfloat16(x1.w); u[7] = *(unsigned short*)&h;
        *(ushort8*)((unsigned short*)xb + base) = u;
    } else {
        // ---- decode + rotate (one 16x128 strip per wave) ----
        __shared__ uint32_t sw[1024];                  // 32 tiles x 32 words
        __shared__ __hip_bfloat16 Hs[128 * 136];       // H[n][k], +8 pad
        const int b = blockIdx.x - CONV_BLOCKS;
        const int tbx = b >> 3;            // out-row tile (0..255)
        const int g0 = (b & 7) * 4;        // first 128-group of this block
        {
            int4 v = *((const int4*)(trellis + ((long)tbx * 256 + g0 * 8) * 32) + tid);
            sw[tid * 4 + 0] = (uint32_t)v.x & 0xFFFFu;
            sw[tid * 4 + 1] = (uint32_t)v.y & 0xFFFFu;
            sw[tid * 4 + 2] = (uint32_t)v.z & 0xFFFFu;
            sw[tid * 4 + 3] = (uint32_t)v.w & 0xFFFFu;
        }
        {
            const int n = tid >> 1;
            const int k0 = (tid & 1) * 64;
            const unsigned short pos = 0x3F80, neg = 0xBF80;
#pragma unroll 8
            for (int k = 0; k < 64; k++) {
                unsigned short s = (__popc(n & (k0 + k)) & 1) ? neg : pos;
                *((unsigned short*)Hs + n * 136 + k0 + k) = s;
            }
        }
        __syncthreads();

        const int wave = tid >> 6;
        const int lane = tid & 63;
        const int m = lane & 15;
        const int quad = lane >> 4;
        const int g = g0 + wave;

        bf16x8 af[4];
#pragma unroll
        for (int kc = 0; kc < 4; kc++) {
            float v[8];
#pragma unroll
            for (int j = 0; j < 8; j++) {
                const int k = kc * 32 + quad * 8 + j;
                const int tile = wave * 8 + (k >> 4);
                const int c = k & 15;
                const int t = m * 16 + c;
                const int q = t >> 3;
                const int rb = (c & 7) * 2;
                const uint32_t w0 = sw[tile * 32 + q];
                const uint32_t w1 = sw[tile * 32 + ((q + 1) & 31)];
                const uint32_t st = ((w0 << rb) | (w1 >> (16 - rb))) & 0xFFFFu;
                v[j] = tlut[st];
            }
#pragma unroll
            for (int j = 0; j < 8; j++) {
                __hip_bfloat16 h = __float2bfloat16(v[j]);
                af[kc][j] = *(short*)&h;
            }
        }
        float scl[4];
#pragma unroll
        for (int r = 0; r < 4; r++)
            scl[r] = scales[(tbx * 16 + quad * 4 + r) * 32 + g] * 0.088388347648318447f;

#pragma unroll
        for (int nt = 0; nt < 8; nt++) {
            f32x4 c = {};
#pragma unroll
            for (int kc = 0; kc < 4; kc++) {
                bf16x8 bf = *(const bf16x8*)&Hs[(nt * 16 + m) * 136 + kc * 32 + quad * 8];
                c = __builtin_amdgcn_mfma_f32_16x16x32_bf16(af[kc], bf, c, 0, 0, 0);
            }
            const long col = (long)g * 128 + nt * 16 + m;
#pragma unroll
            for (int r = 0; r < 4; r++) {
                const long orow = tbx * 16 + quad * 4 + r;
                wb[orow * K_TOT + col] = __float2bfloat16(c[r] * scl[r]);
            }
        }
    }
}

// ---------------- bf16 GEMM: C[m,n] = sum_k A[m,k]*B[n,k]  (both K-contig) --
// m97 structure + XCD-compact swizzle: assuming xcd = lin % 8 (round-robin),
// XCD x owns n-tiles [4x,4x+4) (B slab = 4 MB = one XCD L2), m-major within.
// Concurrent blocks per XCD form a compact ~16m x 4n region -> B L2-resident,
// A L3-resident, HBM/L3 refetch collapses.
__global__ __launch_bounds__(256) void gemm_k(const __hip_bfloat16* __restrict__ A,
                                              const __hip_bfloat16* __restrict__ B,
                                              float* __restrict__ C) {
    __shared__ __align__(16) __hip_bfloat16 sA[128 * 32];
    __shared__ __align__(16) __hip_bfloat16 sB[128 * 32];
    const int t = threadIdx.x;
    const int lane = t & 63;
    const int wave = t >> 6;

    const int lin = blockIdx.x;
    const int xcd = lin & 7;
    const int i = lin >> 3;            // 0..255 within XCD
    const int nt = xcd * 4 + (i & 3);  // n-tile 0..31
    const int mt = i >> 2;             // m-tile 0..63
    const long m0 = (long)mt * 128;
    const long n0 = (long)nt * 128;

    const int srow = t >> 2;
    const int sseg = t & 3;
    const __hip_bfloat16* gA0 = A + (m0 + srow) * K_TOT + sseg * 8;
    const __hip_bfloat16* gA1 = gA0 + (long)64 * K_TOT;
    const __hip_bfloat16* gB0 = B + (n0 + srow) * K_TOT + sseg * 8;
    const __hip_bfloat16* gB1 = gB0 + (long)64 * K_TOT;
    char* dA0 = (char*)sA + wave * 1024;
    char* dA1 = (char*)sA + 4096 + wave * 1024;
    char* dB0 = (char*)sB + wave * 1024;
    char* dB1 = (char*)sB + 4096 + wave * 1024;

    const int mtb = (wave & 1) * 64;
    const int ntb = (wave >> 1) * 64;
    const int lr = lane & 15;
    const int lq = lane >> 4;

    f32x4 acc[4][4] = {};

    for (int kk = 0; kk < K_TOT; kk += 32) {
        __builtin_amdgcn_global_load_lds(GLB(gA0 + kk), LDSP(dA0), 16, 0, 0);
        __builtin_amdgcn_global_load_lds(GLB(gA1 + kk), LDSP(dA1), 16, 0, 0);
        __builtin_amdgcn_global_load_lds(GLB(gB0 + kk), LDSP(dB0), 16, 0, 0);
        __builtin_amdgcn_global_load_lds(GLB(gB1 + kk), LDSP(dB1), 16, 0, 0);
        __syncthreads();

        bf16x8 af[4], bfr[4];
#pragma unroll
        for (int i2 = 0; i2 < 4; i2++) {
            af[i2]  = *(const bf16x8*)&sA[(mtb + i2 * 16 + lr) * 32 + lq * 8];
            bfr[i2] = *(const bf16x8*)&sB[(ntb + i2 * 16 + lr) * 32 + lq * 8];
        }
#pragma unroll
        for (int i2 = 0; i2 < 4; i2++)
#pragma unroll
            for (int j = 0; j < 4; j++)
                acc[i2][j] = __builtin_amdgcn_mfma_f32_16x16x32_bf16(af[i2], bfr[j], acc[i2][j], 0, 0, 0);
        __syncthreads();
    }

    // C/D layout: col = lane&15, row = (lane>>4)*4 + reg
#pragma unroll
    for (int i2 = 0; i2 < 4; i2++)
#pragma unroll
        for (int j = 0; j < 4; j++) {
            const long m = m0 + mtb + i2 * 16 + lq * 4;
            const long n = n0 + ntb + j * 16 + lr;
            float* cp = C + m * N_TOT + n;
#pragma unroll
            for (int r = 0; r < 4; r++)
                cp[(long)r * N_TOT] = acc[i2][j][r];
        }
}

extern "C" void kernel_launch(void* const* d_in, const int* in_sizes, int n_in,
                              void* d_out, int out_size, void* d_ws, size_t ws_size,
                              hipStream_t stream) {
    const float* inp     = (const float*)d_in[0];   // (4,2048,4096) fp32
    const int*   trellis = (const int*)d_in[1];     // (65536,32) int32 (16-bit words)
    const float* tlut    = (const float*)d_in[2];   // (65536,1) fp32
    const float* scales  = (const float*)d_in[3];   // (131072,1) fp32
    float* out = (float*)d_out;                     // (4,2048,4096) fp32

    __hip_bfloat16* xb = (__hip_bfloat16*)d_ws;               // 64 MB
    __hip_bfloat16* wb = xb + (size_t)MROWS * K_TOT;          // 32 MB

    hipLaunchKernelGGL(prep_k, dim3(CONV_BLOCKS + DEC_BLOCKS), dim3(256), 0, stream,
                       inp, trellis, tlut, scales, xb, wb);
    hipLaunchKernelGGL(gemm_k, dim3((MROWS / 128) * (N_TOT / 128)), dim3(256), 0, stream,
                       xb, wb, out);
}